// Round 2
// baseline (635.969 us; speedup 1.0000x reference)
//
#include <hip/hip_runtime.h>

#define NB 256
#define NN 64
#define NT 4096

// K1: variance per (b,i) row over 4096 elements, ddof=1.
// One wave per row, 4 rows per block: 16 float4 loads/lane (256 B/lane),
// pure shuffle reduction -> no LDS, no __syncthreads.
__global__ __launch_bounds__(256) void var_kernel(const float* __restrict__ x,
                                                  float* __restrict__ e) {
    int row  = blockIdx.x * 4 + (threadIdx.x >> 6);
    int lane = threadIdx.x & 63;
    const float4* xr = (const float4*)(x + (size_t)row * NT);
    float s = 0.f, ss = 0.f;
#pragma unroll
    for (int k = 0; k < 16; ++k) {
        float4 v = xr[lane + k * 64];
        s  += (v.x + v.y) + (v.z + v.w);
        ss += (v.x * v.x + v.y * v.y) + (v.z * v.z + v.w * v.w);
    }
#pragma unroll
    for (int off = 32; off > 0; off >>= 1) {
        s  += __shfl_down(s, off);
        ss += __shfl_down(ss, off);
    }
    if (lane == 0) {
        float mean = s * (1.0f / NT);
        e[row] = (ss - (float)NT * mean * mean) * (1.0f / (NT - 1));
    }
}

// K2: softmax attention weights per batch. Logits factor as
// SCALE*(A*e_i*e_j + Bq*e_i + Bk*e_j + C). One thread per row i.
// Writes attn to d_out AND W'^T (transposed, residual identity folded:
// diagonal softmax weight is exactly 0 since exp(-1e9 - m) underflows,
// so W'[i][i] = 1 exactly) to workspace. The TRANSPOSED layout makes
// each j-slice W'T[j][0..63] contiguous -> out_kernel fetches it with
// scalar s_loads, and the store here is lane-coalesced.
__global__ __launch_bounds__(64) void attn_kernel(const float* __restrict__ e,
                                                  const float* __restrict__ wq,
                                                  const float* __restrict__ bq,
                                                  const float* __restrict__ wk,
                                                  const float* __restrict__ bk,
                                                  float* __restrict__ attn_out,
                                                  float* __restrict__ wpT) {
    int b = blockIdx.x;
    int i = threadIdx.x;
    float A = 0.f, Bq = 0.f, Bk = 0.f, C = 0.f;
#pragma unroll
    for (int h = 0; h < 16; ++h) {
        A  += wq[h] * wk[h];
        Bq += wq[h] * bk[h];
        Bk += bq[h] * wk[h];
        C  += bq[h] * bk[h];
    }
    __shared__ float es[NN];
    es[i] = e[b * NN + i];
    __syncthreads();
    float ei = es[i];
    float l[NN];
    float m = -3.0e38f;
#pragma unroll
    for (int j = 0; j < NN; ++j) {
        float v = 0.25f * (A * ei * es[j] + Bq * ei + Bk * es[j] + C);
        if (j == i) v = -1.0e9f;   // diagonal mask
        l[j] = v;
        m = fmaxf(m, v);
    }
    float sum = 0.f;
#pragma unroll
    for (int j = 0; j < NN; ++j) {
        float ev = expf(l[j] - m);  // diagonal underflows to exactly 0
        l[j] = ev;
        sum += ev;
    }
    float inv = 1.0f / sum;
    float* dst = attn_out + (size_t)b * (NN * NN) + i * NN;
    float* wt  = wpT      + (size_t)b * (NN * NN);
#pragma unroll
    for (int j = 0; j < NN; ++j) {
        float w = l[j] * inv;
        dst[j] = w;                              // attn row (thread-local)
        wt[j * NN + i] = (j == i) ? 1.0f : w;    // W'^T, coalesced over lanes
    }
}

// K3: out[b,i,t] = sum_j W'[i][j] * x[b,j,t]  with W' = attn + I.
// Thread owns ONE column t and all 64 output rows as acc[64].
// KEY: the j-loop trip count is laundered through inline asm into an
// SGPR. With a *runtime* bound the compiler cannot fully unroll the
// 64x64 nest and re-group it by output row (which is what rematerialized
// the x loads and produced VGPR_Count=36 + ~4096 L1 loads/thread in the
// previous two versions -> VMEM-issue bound at ~109us floor). With the
// loop opaque, acc[64] is live across iterations and MUST hold VGPRs.
// Per j: 1 x load (x read exactly once per thread, software-pipelined
// over the 64 FMAs) + 64 FMAs against wave-uniform W'T[j][.] (scalar
// cache s_loads, zero VALU/VMEM cost). launch_bounds(256,2) gives
// regalloc a 256-VGPR budget so nothing spills (~80 used, 6 waves/SIMD).
__global__ __launch_bounds__(256, 2) void out_kernel(const float* __restrict__ x,
                                                     const float* __restrict__ WpT,
                                                     float* __restrict__ out) {
    int blk = blockIdx.x;
    int b = blk >> 4;                 // 16 chunks of 256 columns per batch
    int t = (blk & 15) * 256 + threadIdx.x;
    const float* xb = x + (size_t)b * (NN * NT) + t;
    const float* Wb = WpT + (size_t)b * (NN * NN);

    float acc[NN];
#pragma unroll
    for (int i = 0; i < NN; ++i) acc[i] = 0.f;

    int nn = NN;
    asm volatile("" : "+s"(nn));      // opaque trip count

    float xv = xb[0];
    for (int j = 0; j < nn - 1; ++j) {
        float xn = xb[(size_t)(j + 1) * NT];   // prefetch next column value
        const float* Wr = Wb + j * NN;         // wave-uniform -> s_loads
#pragma unroll
        for (int i = 0; i < NN; ++i) acc[i] = fmaf(Wr[i], xv, acc[i]);
        xv = xn;
    }
    {   // final iteration (j = nn-1), no prefetch
        const float* Wr = Wb + (nn - 1) * NN;
#pragma unroll
        for (int i = 0; i < NN; ++i) acc[i] = fmaf(Wr[i], xv, acc[i]);
    }

    float* ob = out + (size_t)b * (NN * NT) + t;
#pragma unroll
    for (int i = 0; i < NN; ++i) ob[(size_t)i * NT] = acc[i];
}

extern "C" void kernel_launch(void* const* d_in, const int* in_sizes, int n_in,
                              void* d_out, int out_size, void* d_ws, size_t ws_size,
                              hipStream_t stream) {
    const float* x  = (const float*)d_in[0];
    const float* wq = (const float*)d_in[1];
    const float* bq = (const float*)d_in[2];
    const float* wk = (const float*)d_in[3];
    const float* bk = (const float*)d_in[4];
    float* out  = (float*)d_out;
    float* attn = out + (size_t)NB * NN * NT;     // second output region
    float* e    = (float*)d_ws;                   // 16384 floats
    float* wpT  = (float*)d_ws + NB * NN;         // W'^T = (attn + I)^T, 4 MB

    var_kernel<<<NB * NN / 4, 256, 0, stream>>>(x, e);
    attn_kernel<<<NB, 64, 0, stream>>>(e, wq, bq, wk, bk, attn, wpT);
    out_kernel<<<NB * 16, 256, 0, stream>>>(x, wpT, out);
}

// Round 3
// 552.973 us; speedup vs baseline: 1.1501x; 1.1501x over previous
//
#include <hip/hip_runtime.h>

#define NB 256
#define NN 64
#define NT 4096

// K1: variance per (b,i) row over 4096 elements, ddof=1.
// One wave per row, 4 rows per block: 16 float4 loads/lane (256 B/lane),
// pure shuffle reduction -> no LDS, no __syncthreads.
__global__ __launch_bounds__(256) void var_kernel(const float* __restrict__ x,
                                                  float* __restrict__ e) {
    int row  = blockIdx.x * 4 + (threadIdx.x >> 6);
    int lane = threadIdx.x & 63;
    const float4* xr = (const float4*)(x + (size_t)row * NT);
    float s = 0.f, ss = 0.f;
#pragma unroll
    for (int k = 0; k < 16; ++k) {
        float4 v = xr[lane + k * 64];
        s  += (v.x + v.y) + (v.z + v.w);
        ss += (v.x * v.x + v.y * v.y) + (v.z * v.z + v.w * v.w);
    }
#pragma unroll
    for (int off = 32; off > 0; off >>= 1) {
        s  += __shfl_down(s, off);
        ss += __shfl_down(ss, off);
    }
    if (lane == 0) {
        float mean = s * (1.0f / NT);
        e[row] = (ss - (float)NT * mean * mean) * (1.0f / (NT - 1));
    }
}

// K2: softmax attention weights per batch. Logits factor as
// SCALE*(A*e_i*e_j + Bq*e_i + Bk*e_j + C). One thread per row i.
// Writes attn to d_out AND W'^T (residual identity folded: diagonal
// softmax weight is exactly 0 since exp(-1e9 - m) underflows, so
// W'[i][i] = 1 exactly) to workspace.
// attn rows are transposed through a padded LDS tile so the d_out store
// is lane-coalesced (direct row store was 64 lanes * 256B stride =
// 4096 cache-line touches per store sweep). W'^T store is naturally
// coalesced (lane i contiguous for fixed j).
__global__ __launch_bounds__(64) void attn_kernel(const float* __restrict__ e,
                                                  const float* __restrict__ wq,
                                                  const float* __restrict__ bq,
                                                  const float* __restrict__ wk,
                                                  const float* __restrict__ bk,
                                                  float* __restrict__ attn_out,
                                                  float* __restrict__ wpT) {
    int b = blockIdx.x;
    int i = threadIdx.x;
    float A = 0.f, Bq = 0.f, Bk = 0.f, C = 0.f;
#pragma unroll
    for (int h = 0; h < 16; ++h) {
        A  += wq[h] * wk[h];
        Bq += wq[h] * bk[h];
        Bk += bq[h] * wk[h];
        C  += bq[h] * bk[h];
    }
    __shared__ float es[NN];
    __shared__ float tr[NN][NN + 1];   // +1 pad: conflict-free row write
    es[i] = e[b * NN + i];
    __syncthreads();
    float ei = es[i];
    float l[NN];
    float m = -3.0e38f;
#pragma unroll
    for (int j = 0; j < NN; ++j) {
        float v = 0.25f * (A * ei * es[j] + Bq * ei + Bk * es[j] + C);
        if (j == i) v = -1.0e9f;   // diagonal mask
        l[j] = v;
        m = fmaxf(m, v);
    }
    float sum = 0.f;
#pragma unroll
    for (int j = 0; j < NN; ++j) {
        float ev = expf(l[j] - m);  // diagonal underflows to exactly 0
        l[j] = ev;
        sum += ev;
    }
    float inv = 1.0f / sum;
    float* wt = wpT + (size_t)b * (NN * NN);
#pragma unroll
    for (int j = 0; j < NN; ++j) {
        float w = l[j] * inv;
        tr[i][j] = w;                            // LDS, bank-safe via pad
        wt[j * NN + i] = (j == i) ? 1.0f : w;    // W'^T, coalesced
    }
    __syncthreads();
    float* dst = attn_out + (size_t)b * (NN * NN);
#pragma unroll
    for (int r = 0; r < NN; ++r)
        dst[r * NN + i] = tr[r][i];              // coalesced row store
}

// K3: out[b,i,t] = sum_j W'[i][j] * x[b,j,t]  with W' = attn + I.
// Register-tile structure the compiler actually keeps in registers:
// per-thread tile = 8 rows x 4 cols -> acc is 8 float4 = 32 VGPRs
// (round 1: xv[64] cache got rematerialized into ~4096 L1 loads, VGPR=36;
// round 2: opaque-loop acc[64] got SPILLED to scratch, VGPR=36, slower.
// 32 accumulators is within what regalloc will happily keep live).
// Block = 512 threads = 8 waves; wave w owns output rows [8w, 8w+8);
// lanes own 4 columns each -> block covers a disjoint 256-column stripe,
// so x is fetched from HBM exactly once per element. W'^T slice (16 KB)
// is staged in LDS; each wave's W read address is wave-uniform -> LDS
// broadcast, conflict-free (a wave-varying global offset would have
// blocked s_load uniformity, which is why LDS and not scalar loads).
// Per j: 1 float4 x load + 32 FMAs. FMA floor 54.6us, HBM floor ~86us
// -> memory-bound.
__global__ __launch_bounds__(512, 2) void out_kernel(const float* __restrict__ x,
                                                     const float* __restrict__ WpT,
                                                     float* __restrict__ out) {
    __shared__ float sW[NN * NN];     // 16 KB W'^T for this batch
    int blk = blockIdx.x;
    int b = blk >> 4;                 // 16 stripes of 256 columns per batch
    int stripe = blk & 15;
    int tid = threadIdx.x;
    int wave = tid >> 6;              // row group: rows [8*wave, 8*wave+8)
    int lane = tid & 63;

    {   // stage W'^T: 4096 floats = 1024 float4, 512 threads x 2, coalesced
        const float4* src = (const float4*)(WpT + (size_t)b * (NN * NN));
        float4* dst = (float4*)sW;
        dst[tid]       = src[tid];
        dst[tid + 512] = src[tid + 512];
    }
    __syncthreads();

    int t = stripe * 256 + lane * 4;
    const float* xb = x + (size_t)b * (NN * NT) + t;

    float4 acc[8];
#pragma unroll
    for (int r = 0; r < 8; ++r) acc[r] = make_float4(0.f, 0.f, 0.f, 0.f);

    const float* sWr = sW + wave * 8;
#pragma unroll 8
    for (int j = 0; j < NN; ++j) {
        float4 xv = *(const float4*)(xb + (size_t)j * NT);
        const float* w = sWr + j * NN;   // wave-uniform -> LDS broadcast
#pragma unroll
        for (int r = 0; r < 8; ++r) {
            float wr = w[r];
            acc[r].x = fmaf(wr, xv.x, acc[r].x);
            acc[r].y = fmaf(wr, xv.y, acc[r].y);
            acc[r].z = fmaf(wr, xv.z, acc[r].z);
            acc[r].w = fmaf(wr, xv.w, acc[r].w);
        }
    }

    float* ob = out + (size_t)b * (NN * NT) + (size_t)(wave * 8) * NT + t;
#pragma unroll
    for (int r = 0; r < 8; ++r)
        *(float4*)(ob + (size_t)r * NT) = acc[r];
}

extern "C" void kernel_launch(void* const* d_in, const int* in_sizes, int n_in,
                              void* d_out, int out_size, void* d_ws, size_t ws_size,
                              hipStream_t stream) {
    const float* x  = (const float*)d_in[0];
    const float* wq = (const float*)d_in[1];
    const float* bq = (const float*)d_in[2];
    const float* wk = (const float*)d_in[3];
    const float* bk = (const float*)d_in[4];
    float* out  = (float*)d_out;
    float* attn = out + (size_t)NB * NN * NT;     // second output region
    float* e    = (float*)d_ws;                   // 16384 floats
    float* wpT  = (float*)d_ws + NB * NN;         // W'^T = (attn + I)^T, 4 MB

    var_kernel<<<NB * NN / 4, 256, 0, stream>>>(x, e);
    attn_kernel<<<NB, 64, 0, stream>>>(e, wq, bq, wk, bk, attn, wpT);
    out_kernel<<<NB * 16, 512, 0, stream>>>(x, wpT, out);
}